// Round 1
// baseline (802.962 us; speedup 1.0000x reference)
//
#include <hip/hip_runtime.h>

#define N_PIX 4096
#define CCH 256
#define DQK 16
#define DV 128

// ---------------------------------------------------------------------------
// K1: fused 1x1 convs -> q[2][B][16][N], k[2][B][16][N], vT[2][B][N][128]
// grid (64, 4): x = pixel tile (64 px), y = input*2 + batch
// ---------------------------------------------------------------------------
__global__ __launch_bounds__(256) void qkv_kernel(
    const float* __restrict__ x1, const float* __restrict__ x2,
    const float* __restrict__ Wq, const float* __restrict__ bq,
    const float* __restrict__ Wk, const float* __restrict__ bk,
    const float* __restrict__ Wv, const float* __restrict__ bv,
    float* __restrict__ q, float* __restrict__ k, float* __restrict__ vT)
{
    __shared__ float xs[CCH][64];
    const int tid = threadIdx.x;
    const int n0 = blockIdx.x * 64;
    const int i  = blockIdx.y >> 1, b = blockIdx.y & 1;
    const float* x = (i == 0 ? x1 : x2) + (size_t)b * CCH * N_PIX;

    for (int idx = tid; idx < CCH * 64; idx += 256) {
        int c = idx >> 6, px = idx & 63;
        xs[c][px] = x[(size_t)c * N_PIX + n0 + px];
    }
    __syncthreads();

    const int w = tid >> 6, px = tid & 63;
    const int ib = i * 2 + b;

    for (int rt = 0; rt < 5; ++rt) {
        int r0 = w * 40 + rt * 8;   // groups of 8 rows, uniform type (q/k/v)
        const float* Wp; const float* bp;
        if (r0 < 16)      { Wp = Wq + (size_t)r0 * CCH;        bp = bq + r0; }
        else if (r0 < 32) { Wp = Wk + (size_t)(r0 - 16) * CCH; bp = bk + (r0 - 16); }
        else              { Wp = Wv + (size_t)(r0 - 32) * CCH; bp = bv + (r0 - 32); }

        float acc[8];
        #pragma unroll
        for (int j = 0; j < 8; ++j) acc[j] = bp[j];

        #pragma unroll 4
        for (int c = 0; c < CCH; ++c) {
            float xv = xs[c][px];
            #pragma unroll
            for (int j = 0; j < 8; ++j)
                acc[j] += Wp[(size_t)j * CCH + c] * xv;
        }

        if (r0 < 16) {
            #pragma unroll
            for (int j = 0; j < 8; ++j)
                q[((size_t)ib * DQK + r0 + j) * N_PIX + n0 + px] = acc[j];
        } else if (r0 < 32) {
            #pragma unroll
            for (int j = 0; j < 8; ++j)
                k[((size_t)ib * DQK + (r0 - 16) + j) * N_PIX + n0 + px] = acc[j];
        } else {
            #pragma unroll
            for (int j = 0; j < 8; ++j)
                vT[((size_t)ib * N_PIX + n0 + px) * DV + (r0 - 32) + j] = acc[j];
        }
    }
}

// ---------------------------------------------------------------------------
// K2: streaming attention (single-pass, no-max softmax: scores bounded) +
//     epilogue: out = gamma * concat(attn_out, x_self[:128]) + x_self
// grid (128, 4): x = 32-row tile, y = branch*2 + batch. block = 256
// ---------------------------------------------------------------------------
__global__ __launch_bounds__(256) void attn_kernel(
    const float* __restrict__ qg, const float* __restrict__ kg,
    const float* __restrict__ vTg,
    const float* __restrict__ x1, const float* __restrict__ x2,
    const float* __restrict__ gamma_p,
    float* __restrict__ out1, float* __restrict__ out2)
{
    __shared__ float qs[DQK][32];
    __shared__ float ks[DQK][64];
    __shared__ float sc[32][65];
    __shared__ float vs[64 * 128];     // reused as os[32][129] after main loop
    __shared__ float linv[32];

    const int tid = threadIdx.x;
    const int n0 = blockIdx.x * 32;
    const int br = blockIdx.y >> 1, b = blockIdx.y & 1;

    const float* qp = qg  + ((size_t)(br * 2 + b)) * DQK * N_PIX;
    const float* kp = kg  + ((size_t)((br ^ 1) * 2 + b)) * DQK * N_PIX;
    const float* vp = vTg + ((size_t)(br * 2 + b)) * N_PIX * DV;
    const float* xsg = (br ? x2 : x1) + (size_t)b * CCH * N_PIX;
    float* op = (br ? out2 : out1) + (size_t)b * CCH * N_PIX;

    for (int idx = tid; idx < DQK * 32; idx += 256) {
        int d = idx >> 5, rr = idx & 31;
        qs[d][rr] = qp[(size_t)d * N_PIX + n0 + rr];
    }

    const int sr = tid >> 3, sj = tid & 7;      // score phase: row, m-chunk
    const int g = tid >> 5, cw = tid & 31;      // acc phase: row group, chan
    float acc[4][4] = {};                        // [row-in-group][c component]
    float lsum = 0.f;
    float4* vs4 = (float4*)vs;
    __syncthreads();

    for (int t = 0; t < 64; ++t) {
        const int m0 = t * 64;
        {   // load k tile 16x64 (coalesced)
            int d = tid >> 6, mm = tid & 63;
            #pragma unroll
            for (int dd = 0; dd < 16; dd += 4)
                ks[d + dd][mm] = kp[(size_t)(d + dd) * N_PIX + m0 + mm];
        }
        {   // load v tile 64x128 (fully contiguous float4)
            const float4* vsrc = (const float4*)(vp + (size_t)m0 * DV);
            #pragma unroll
            for (int idx = tid; idx < 2048; idx += 256)
                vs4[idx] = vsrc[idx];
        }
        __syncthreads();

        // scores -> exp -> sc
        #pragma unroll
        for (int ii = 0; ii < 8; ++ii) {
            int mm = sj * 8 + ii;
            float s = 0.f;
            #pragma unroll
            for (int d = 0; d < DQK; ++d) s += qs[d][sr] * ks[d][mm];
            float e = __expf(s * 0.25f);
            sc[sr][mm] = e;
            lsum += e;
        }
        __syncthreads();

        // accumulate out += exp(s) * v
        for (int mm = 0; mm < 64; ++mm) {
            float4 v4 = vs4[mm * 32 + cw];
            #pragma unroll
            for (int rr = 0; rr < 4; ++rr) {
                float p = sc[g * 4 + rr][mm];
                acc[rr][0] += p * v4.x;
                acc[rr][1] += p * v4.y;
                acc[rr][2] += p * v4.z;
                acc[rr][3] += p * v4.w;
            }
        }
        __syncthreads();
    }

    // reduce l over the 8 m-chunk lanes
    lsum += __shfl_xor(lsum, 1);
    lsum += __shfl_xor(lsum, 2);
    lsum += __shfl_xor(lsum, 4);
    if (sj == 0) linv[sr] = 1.0f / lsum;
    __syncthreads();

    // normalize into os (reuse vs region). os[32][129]
    float* os = vs;
    #pragma unroll
    for (int rr = 0; rr < 4; ++rr) {
        float li = linv[g * 4 + rr];
        #pragma unroll
        for (int qq = 0; qq < 4; ++qq)
            os[(g * 4 + rr) * 129 + 4 * cw + qq] = acc[rr][qq] * li;
    }
    __syncthreads();

    const float gmm = gamma_p[0];
    for (int idx = tid; idx < CCH * 32; idx += 256) {
        int c = idx >> 5, nn = idx & 31;
        float xv = xsg[(size_t)c * N_PIX + n0 + nn];
        float val;
        if (c < 128) val = gmm * os[nn * 129 + c] + xv;
        else         val = gmm * xsg[(size_t)(c - 128) * N_PIX + n0 + nn] + xv;
        op[(size_t)c * N_PIX + n0 + nn] = val;
    }
}

// ---------------------------------------------------------------------------
// K3: 3x3 conv (SAME) on s = out1 + out2, + BN(inference) + ReLU
// grid (16, 8, 2): x = 4x4 spatial tiles of 16x16, y = oc/32, z = batch
// thread: oi = tid>>4 (oc pair), r = tid&15 (row); owns 2 oc x 16 cols
// ---------------------------------------------------------------------------
__global__ __launch_bounds__(256) void conv_kernel(
    const float* __restrict__ out1, const float* __restrict__ out2,
    const float* __restrict__ Wcat, const float* __restrict__ bn_gamma,
    const float* __restrict__ bn_beta, float* __restrict__ feat)
{
    __shared__ float ins[8][18][18];
    __shared__ float wsm[32][8][9];

    const int tid = threadIdx.x;
    const int b = blockIdx.z;
    const int oc0 = blockIdx.y * 32;
    const int th = (blockIdx.x >> 2) * 16, tw = (blockIdx.x & 3) * 16;
    const int oi = tid >> 4;
    const int r  = tid & 15;

    const float* s1 = out1 + (size_t)b * CCH * N_PIX;
    const float* s2 = out2 + (size_t)b * CCH * N_PIX;

    float acc[2][16] = {};

    for (int ic0 = 0; ic0 < CCH; ic0 += 8) {
        __syncthreads();
        // input tile 8 x 18 x 18 with zero SAME padding, s = out1 + out2
        for (int idx = tid; idx < 8 * 18 * 18; idx += 256) {
            int ic = idx / 324, rem = idx % 324;
            int dy = rem / 18, dx = rem % 18;
            int h = th - 1 + dy, w = tw - 1 + dx;
            float v = 0.f;
            if (h >= 0 && h < 64 && w >= 0 && w < 64) {
                size_t off = (size_t)(ic0 + ic) * N_PIX + h * 64 + w;
                v = s1[off] + s2[off];
            }
            ((float*)ins)[idx] = v;
        }
        // weights 32 oc x 8 ic x 9
        for (int idx = tid; idx < 32 * 8 * 9; idx += 256) {
            int o = idx / 72, rem = idx % 72;
            ((float*)wsm)[idx] = Wcat[(size_t)(oc0 + o) * (CCH * 9) + (size_t)ic0 * 9 + rem];
        }
        __syncthreads();

        for (int ic = 0; ic < 8; ++ic) {
            #pragma unroll
            for (int ky = 0; ky < 3; ++ky) {
                float rb[18];
                #pragma unroll
                for (int j = 0; j < 18; ++j) rb[j] = ins[ic][r + ky][j];
                #pragma unroll
                for (int o2 = 0; o2 < 2; ++o2) {
                    #pragma unroll
                    for (int kx = 0; kx < 3; ++kx) {
                        float wv = wsm[oi * 2 + o2][ic][ky * 3 + kx];
                        #pragma unroll
                        for (int kk = 0; kk < 16; ++kk)
                            acc[o2][kk] += wv * rb[kk + kx];
                    }
                }
            }
        }
    }

    const float inv = rsqrtf(1.0f + 1e-5f);
    #pragma unroll
    for (int o2 = 0; o2 < 2; ++o2) {
        int oc = oc0 + oi * 2 + o2;
        float scale = bn_gamma[oc] * inv, beta = bn_beta[oc];
        #pragma unroll
        for (int kk = 0; kk < 16; ++kk) {
            float y = acc[o2][kk] * scale + beta;
            y = y > 0.f ? y : 0.f;
            feat[((size_t)b * CCH + oc) * N_PIX + (size_t)(th + r) * 64 + tw + kk] = y;
        }
    }
}

// ---------------------------------------------------------------------------
extern "C" void kernel_launch(void* const* d_in, const int* in_sizes, int n_in,
                              void* d_out, int out_size, void* d_ws, size_t ws_size,
                              hipStream_t stream) {
    const float* x1    = (const float*)d_in[0];
    const float* x2    = (const float*)d_in[1];
    const float* Wq    = (const float*)d_in[2];
    const float* bq    = (const float*)d_in[3];
    const float* Wk    = (const float*)d_in[4];
    const float* bk    = (const float*)d_in[5];
    const float* Wv    = (const float*)d_in[6];
    const float* bv    = (const float*)d_in[7];
    const float* gamma = (const float*)d_in[8];
    const float* Wcat  = (const float*)d_in[9];
    const float* bng   = (const float*)d_in[10];
    const float* bnb   = (const float*)d_in[11];

    float* out  = (float*)d_out;
    float* feat = out;                       // (B,256,64,64) = 2,097,152
    float* out1 = out + 2097152;
    float* out2 = out + 4194304;

    float* ws = (float*)d_ws;
    float* q  = ws;                          // 2*2*16*4096   = 262144
    float* k  = ws + 262144;                 // 262144
    float* vT = ws + 524288;                 // 2*2*4096*128  = 2097152

    qkv_kernel<<<dim3(64, 4), 256, 0, stream>>>(x1, x2, Wq, bq, Wk, bk, Wv, bv, q, k, vT);
    attn_kernel<<<dim3(128, 4), 256, 0, stream>>>(q, k, vT, x1, x2, gamma, out1, out2);
    conv_kernel<<<dim3(16, 8, 2), 256, 0, stream>>>(out1, out2, Wcat, bng, bnb, feat);
}

// Round 2
// 483.170 us; speedup vs baseline: 1.6619x; 1.6619x over previous
//
#include <hip/hip_runtime.h>

#define N_PIX 4096
#define CCH 256
#define DV 128

typedef __attribute__((ext_vector_type(8))) short bf16x8;
typedef __attribute__((ext_vector_type(4))) float f32x4;
typedef __attribute__((ext_vector_type(8))) short short8;

__device__ __forceinline__ short f2bf(float f) {
    unsigned u = __builtin_bit_cast(unsigned, f);
    u += 0x7fffu + ((u >> 16) & 1u);
    return (short)(u >> 16);
}

// ---------------------------------------------------------------------------
// K1: fused 1x1 convs (register-tiled fp32 GEMM, W staged in LDS) ->
//     qb[ib][n][16] bf16, kb[ib][n][16] bf16, vb[ib][c][N] bf16
// grid (64, 4): x = 64-px tile, y = ib (input*2 + batch). block 256.
// thread tile: 5 rows x 8 px (32 row-groups x 8 px-groups)
// ---------------------------------------------------------------------------
__global__ __launch_bounds__(256) void qkv_kernel(
    const float* __restrict__ x1, const float* __restrict__ x2,
    const float* __restrict__ Wq, const float* __restrict__ bq,
    const float* __restrict__ Wk, const float* __restrict__ bk,
    const float* __restrict__ Wv, const float* __restrict__ bv,
    short* __restrict__ qb, short* __restrict__ kb, short* __restrict__ vb)
{
    __shared__ float xs[64][64];
    __shared__ float wsm[160][65];
    const int tid = threadIdx.x;
    const int n0 = blockIdx.x * 64;
    const int i = blockIdx.y >> 1, b = blockIdx.y & 1;
    const float* x = (i == 0 ? x1 : x2) + (size_t)b * CCH * N_PIX;
    const int ib = blockIdx.y;
    const int rg = tid >> 3, pg = tid & 7;
    const int r0 = rg * 5, px0 = pg * 8;
    float acc[5][8] = {};

    for (int c0 = 0; c0 < CCH; c0 += 64) {
        __syncthreads();
        for (int idx = tid; idx < 1024; idx += 256) {
            int c = idx >> 4, q4 = idx & 15;
            float4 v = *(const float4*)&x[(size_t)(c0 + c) * N_PIX + n0 + q4 * 4];
            *(float4*)&xs[c][q4 * 4] = v;
        }
        for (int idx = tid; idx < 2560; idx += 256) {
            int rr = idx >> 4, c4 = idx & 15;
            const float* Wsrc;
            if (rr < 16)      Wsrc = Wq + (size_t)rr * CCH;
            else if (rr < 32) Wsrc = Wk + (size_t)(rr - 16) * CCH;
            else              Wsrc = Wv + (size_t)(rr - 32) * CCH;
            float4 wv = *(const float4*)&Wsrc[c0 + c4 * 4];
            wsm[rr][c4 * 4 + 0] = wv.x; wsm[rr][c4 * 4 + 1] = wv.y;
            wsm[rr][c4 * 4 + 2] = wv.z; wsm[rr][c4 * 4 + 3] = wv.w;
        }
        __syncthreads();
        for (int c = 0; c < 64; ++c) {
            float xv[8];
            float4 xa = *(float4*)&xs[c][px0];
            float4 xb = *(float4*)&xs[c][px0 + 4];
            xv[0] = xa.x; xv[1] = xa.y; xv[2] = xa.z; xv[3] = xa.w;
            xv[4] = xb.x; xv[5] = xb.y; xv[6] = xb.z; xv[7] = xb.w;
            #pragma unroll
            for (int j = 0; j < 5; ++j) {
                float wv = wsm[r0 + j][c];
                #pragma unroll
                for (int p2 = 0; p2 < 8; ++p2) acc[j][p2] += wv * xv[p2];
            }
        }
    }

    #pragma unroll
    for (int j = 0; j < 5; ++j) {
        int rr = r0 + j;
        if (rr < 16) {
            float bias = bq[rr];
            for (int p2 = 0; p2 < 8; ++p2)
                qb[((size_t)ib * N_PIX + n0 + px0 + p2) * 16 + rr] = f2bf(acc[j][p2] + bias);
        } else if (rr < 32) {
            float bias = bk[rr - 16];
            for (int p2 = 0; p2 < 8; ++p2)
                kb[((size_t)ib * N_PIX + n0 + px0 + p2) * 16 + (rr - 16)] = f2bf(acc[j][p2] + bias);
        } else {
            float bias = bv[rr - 32];
            short8 s8;
            for (int p2 = 0; p2 < 8; ++p2) s8[p2] = f2bf(acc[j][p2] + bias);
            *(short8*)&vb[((size_t)ib * DV + (rr - 32)) * N_PIX + n0 + px0] = s8;
        }
    }
}

// ---------------------------------------------------------------------------
// K2: MFMA flash attention, O^T = V * P^T formulation + fused epilogue.
// grid 256 (XCD-swizzled), block 256 = 4 waves; wave w owns 16 n-rows.
// Single-pass softmax (scores bounded -> no running max), unnormalized
// P accumulated via mfma, row-sum l in registers, divide at end.
// LDS double-buffered K/V tiles, async-split reg staging.
// ---------------------------------------------------------------------------
__global__ __launch_bounds__(256) void attn_kernel(
    const short* __restrict__ qg, const short* __restrict__ kg,
    const short* __restrict__ vg,
    const float* __restrict__ x1, const float* __restrict__ x2,
    const float* __restrict__ gamma_p,
    float* __restrict__ out1, float* __restrict__ out2)
{
    __shared__ short k_lds[2][32 * 24];   // [m][d], pitch 48B
    __shared__ short v_lds[2][128 * 40];  // [c][m], pitch 80B
    __shared__ short p_lds[4][16 * 40];   // per-wave [n][m], pitch 80B
    __shared__ float l_lds[4][16];

    const int tid = threadIdx.x;
    const int lane = tid & 63;
    const int w = tid >> 6;
    // XCD swizzle: problem p's 64 blocks -> XCDs {2p, 2p+1}
    const int B_ = blockIdx.x;
    const int res = B_ & 7;
    const int p = res >> 1;
    const int xt = ((B_ >> 3) << 1) | (res & 1);
    const int br = p >> 1, b = p & 1;
    const int n0 = xt * 64;

    const short* qp = qg + (size_t)(br * 2 + b) * N_PIX * 16;
    const short* kp = kg + (size_t)((br ^ 1) * 2 + b) * N_PIX * 16;
    const short* vp = vg + (size_t)(br * 2 + b) * DV * N_PIX;
    const float* xsg = (br ? x2 : x1) + (size_t)b * CCH * N_PIX;
    float* op = (br ? out2 : out1) + (size_t)b * CCH * N_PIX;

    const int g = lane >> 4;
    const int l15 = lane & 15;

    // constant Q A-fragment: row n = n0 + w*16 + l15, k=d 0..15 (lanes>=32: zero pad to K=32)
    bf16x8 aq = {};
    if (lane < 32)
        aq = *(const bf16x8*)&qp[((size_t)(n0 + w * 16 + l15)) * 16 + g * 8];

    f32x4 acc[8];
    #pragma unroll
    for (int cc = 0; cc < 8; ++cc) acc[cc] = (f32x4){0.f, 0.f, 0.f, 0.f};
    float lsum[4] = {0.f, 0.f, 0.f, 0.f};

    const int vc = tid >> 1, vh = tid & 1;          // V staging: c-row, 16-m half
    const int kr = (tid - 64) >> 1, kh = tid & 1;   // K staging: tids 64..127

    int4 vr0 = {}, vr1 = {}, kreg = {};
    {   // prologue: chunk 0
        const int4* gsrc = (const int4*)(vp + (size_t)vc * N_PIX + vh * 16);
        vr0 = gsrc[0]; vr1 = gsrc[1];
        if (tid >= 64 && tid < 128)
            kreg = *(const int4*)(kp + (size_t)kr * 16 + kh * 8);
        int4* vd = (int4*)&v_lds[0][vc * 40 + vh * 16];
        vd[0] = vr0; vd[1] = vr1;
        if (tid >= 64 && tid < 128)
            *(int4*)&k_lds[0][kr * 24 + kh * 8] = kreg;
    }
    __syncthreads();

    for (int t = 0; t < 128; ++t) {
        const int cur = t & 1;
        if (t < 127) {  // issue next-chunk global loads (latency hides under compute)
            const int m0n = (t + 1) * 32;
            const int4* gsrc = (const int4*)(vp + (size_t)vc * N_PIX + m0n + vh * 16);
            vr0 = gsrc[0]; vr1 = gsrc[1];
            if (tid >= 64 && tid < 128)
                kreg = *(const int4*)(kp + (size_t)(m0n + kr) * 16 + kh * 8);
        }
        // QK^T (two 16-col m-halves), exp, stash P as bf16 in per-wave LDS
        #pragma unroll
        for (int h = 0; h < 2; ++h) {
            bf16x8 bk_ = {};
            if (lane < 32)
                bk_ = *(const bf16x8*)&k_lds[cur][(h * 16 + l15) * 24 + g * 8];
            f32x4 s = __builtin_amdgcn_mfma_f32_16x16x32_bf16(
                aq, bk_, (f32x4){0.f, 0.f, 0.f, 0.f}, 0, 0, 0);
            #pragma unroll
            for (int rr = 0; rr < 4; ++rr) {
                float e = __expf(s[rr] * 0.25f);
                lsum[rr] += e;
                p_lds[w][(g * 4 + rr) * 40 + h * 16 + l15] = f2bf(e);
            }
        }
        // PV: O^T[c][n] += V[c][m] * P^T[m][n]
        bf16x8 bp = *(const bf16x8*)&p_lds[w][l15 * 40 + g * 8];
        #pragma unroll
        for (int cc = 0; cc < 8; ++cc) {
            bf16x8 av = *(const bf16x8*)&v_lds[cur][(cc * 16 + l15) * 40 + g * 8];
            acc[cc] = __builtin_amdgcn_mfma_f32_16x16x32_bf16(av, bp, acc[cc], 0, 0, 0);
        }
        if (t < 127) {  // write next chunk into the other buffer
            int4* vd = (int4*)&v_lds[cur ^ 1][vc * 40 + vh * 16];
            vd[0] = vr0; vd[1] = vr1;
            if (tid >= 64 && tid < 128)
                *(int4*)&k_lds[cur ^ 1][kr * 24 + kh * 8] = kreg;
        }
        __syncthreads();
    }

    // row-sum reduce across the 16 m-lanes, redistribute by n via LDS
    #pragma unroll
    for (int rr = 0; rr < 4; ++rr) {
        float v = lsum[rr];
        v += __shfl_xor(v, 1); v += __shfl_xor(v, 2);
        v += __shfl_xor(v, 4); v += __shfl_xor(v, 8);
        lsum[rr] = v;
    }
    if (l15 == 0) {
        #pragma unroll
        for (int rr = 0; rr < 4; ++rr) l_lds[w][g * 4 + rr] = lsum[rr];
    }
    const float gmm = gamma_p[0];
    float linv = 1.0f / l_lds[w][l15];
    const int n = n0 + w * 16 + l15;
    #pragma unroll
    for (int cc = 0; cc < 8; ++cc) {
        #pragma unroll
        for (int rr = 0; rr < 4; ++rr) {
            int c = cc * 16 + g * 4 + rr;
            op[(size_t)c * N_PIX + n] = gmm * acc[cc][rr] * linv + xsg[(size_t)c * N_PIX + n];
        }
    }
    // channels 128..255: gamma * x_self[c-128] + x_self[c]
    for (int idx = tid; idx < 128 * 16; idx += 256) {
        int c = (idx >> 4) + 128, q4 = idx & 15;
        float4 xl = *(const float4*)&xsg[(size_t)(c - 128) * N_PIX + n0 + q4 * 4];
        float4 xh = *(const float4*)&xsg[(size_t)c * N_PIX + n0 + q4 * 4];
        float4 o;
        o.x = gmm * xl.x + xh.x; o.y = gmm * xl.y + xh.y;
        o.z = gmm * xl.z + xh.z; o.w = gmm * xl.w + xh.w;
        *(float4*)&op[(size_t)c * N_PIX + n0 + q4 * 4] = o;
    }
}

// ---------------------------------------------------------------------------
// K3: 3x3 conv (SAME) on s = out1 + out2, + BN(inference) + ReLU (unchanged)
// ---------------------------------------------------------------------------
__global__ __launch_bounds__(256) void conv_kernel(
    const float* __restrict__ out1, const float* __restrict__ out2,
    const float* __restrict__ Wcat, const float* __restrict__ bn_gamma,
    const float* __restrict__ bn_beta, float* __restrict__ feat)
{
    __shared__ float ins[8][18][18];
    __shared__ float wsm[32][8][9];

    const int tid = threadIdx.x;
    const int b = blockIdx.z;
    const int oc0 = blockIdx.y * 32;
    const int th = (blockIdx.x >> 2) * 16, tw = (blockIdx.x & 3) * 16;
    const int oi = tid >> 4;
    const int r  = tid & 15;

    const float* s1 = out1 + (size_t)b * CCH * N_PIX;
    const float* s2 = out2 + (size_t)b * CCH * N_PIX;

    float acc[2][16] = {};

    for (int ic0 = 0; ic0 < CCH; ic0 += 8) {
        __syncthreads();
        for (int idx = tid; idx < 8 * 18 * 18; idx += 256) {
            int ic = idx / 324, rem = idx % 324;
            int dy = rem / 18, dx = rem % 18;
            int h = th - 1 + dy, w = tw - 1 + dx;
            float v = 0.f;
            if (h >= 0 && h < 64 && w >= 0 && w < 64) {
                size_t off = (size_t)(ic0 + ic) * N_PIX + h * 64 + w;
                v = s1[off] + s2[off];
            }
            ((float*)ins)[idx] = v;
        }
        for (int idx = tid; idx < 32 * 8 * 9; idx += 256) {
            int o = idx / 72, rem = idx % 72;
            ((float*)wsm)[idx] = Wcat[(size_t)(oc0 + o) * (CCH * 9) + (size_t)ic0 * 9 + rem];
        }
        __syncthreads();

        for (int ic = 0; ic < 8; ++ic) {
            #pragma unroll
            for (int ky = 0; ky < 3; ++ky) {
                float rb[18];
                #pragma unroll
                for (int j = 0; j < 18; ++j) rb[j] = ins[ic][r + ky][j];
                #pragma unroll
                for (int o2 = 0; o2 < 2; ++o2) {
                    #pragma unroll
                    for (int kx = 0; kx < 3; ++kx) {
                        float wv = wsm[oi * 2 + o2][ic][ky * 3 + kx];
                        #pragma unroll
                        for (int kk = 0; kk < 16; ++kk)
                            acc[o2][kk] += wv * rb[kk + kx];
                    }
                }
            }
        }
    }

    const float inv = rsqrtf(1.0f + 1e-5f);
    #pragma unroll
    for (int o2 = 0; o2 < 2; ++o2) {
        int oc = oc0 + oi * 2 + o2;
        float scale = bn_gamma[oc] * inv, beta = bn_beta[oc];
        #pragma unroll
        for (int kk = 0; kk < 16; ++kk) {
            float y = acc[o2][kk] * scale + beta;
            y = y > 0.f ? y : 0.f;
            feat[((size_t)b * CCH + oc) * N_PIX + (size_t)(th + r) * 64 + tw + kk] = y;
        }
    }
}

// ---------------------------------------------------------------------------
extern "C" void kernel_launch(void* const* d_in, const int* in_sizes, int n_in,
                              void* d_out, int out_size, void* d_ws, size_t ws_size,
                              hipStream_t stream) {
    const float* x1    = (const float*)d_in[0];
    const float* x2    = (const float*)d_in[1];
    const float* Wq    = (const float*)d_in[2];
    const float* bq    = (const float*)d_in[3];
    const float* Wk    = (const float*)d_in[4];
    const float* bk    = (const float*)d_in[5];
    const float* Wv    = (const float*)d_in[6];
    const float* bv    = (const float*)d_in[7];
    const float* gamma = (const float*)d_in[8];
    const float* Wcat  = (const float*)d_in[9];
    const float* bng   = (const float*)d_in[10];
    const float* bnb   = (const float*)d_in[11];

    float* out  = (float*)d_out;
    float* feat = out;
    float* out1 = out + 2097152;
    float* out2 = out + 4194304;

    short* ws = (short*)d_ws;
    short* qb = ws;                       // 4*4096*16  = 262144 shorts
    short* kb = ws + 262144;              // 262144
    short* vb = ws + 524288;              // 4*128*4096 = 2097152 shorts

    qkv_kernel<<<dim3(64, 4), 256, 0, stream>>>(x1, x2, Wq, bq, Wk, bk, Wv, bv, qb, kb, vb);
    attn_kernel<<<256, 256, 0, stream>>>(qb, kb, vb, x1, x2, gamma, out1, out2);
    conv_kernel<<<dim3(16, 8, 2), 256, 0, stream>>>(out1, out2, Wcat, bng, bnb, feat);
}

// Round 3
// 170.491 us; speedup vs baseline: 4.7097x; 2.8340x over previous
//
#include <hip/hip_runtime.h>

#define N_PIX 4096
#define CCH 256
#define DV 128

typedef __attribute__((ext_vector_type(8))) short bf16x8;
typedef __attribute__((ext_vector_type(4))) float f32x4;
typedef __attribute__((ext_vector_type(8))) short short8;

__device__ __forceinline__ short f2bf(float f) {
    unsigned u = __builtin_bit_cast(unsigned, f);
    u += 0x7fffu + ((u >> 16) & 1u);
    return (short)(u >> 16);
}

// ---------------------------------------------------------------------------
// K1: fused 1x1 convs (register-tiled fp32 GEMM, W staged in LDS) ->
//     qb[ib][n][16] bf16, kb[ib][n][16] bf16, vb[ib][c][N] bf16
// ---------------------------------------------------------------------------
__global__ __launch_bounds__(256) void qkv_kernel(
    const float* __restrict__ x1, const float* __restrict__ x2,
    const float* __restrict__ Wq, const float* __restrict__ bq,
    const float* __restrict__ Wk, const float* __restrict__ bk,
    const float* __restrict__ Wv, const float* __restrict__ bv,
    short* __restrict__ qb, short* __restrict__ kb, short* __restrict__ vb)
{
    __shared__ float xs[64][64];
    __shared__ float wsm[160][65];
    const int tid = threadIdx.x;
    const int n0 = blockIdx.x * 64;
    const int i = blockIdx.y >> 1, b = blockIdx.y & 1;
    const float* x = (i == 0 ? x1 : x2) + (size_t)b * CCH * N_PIX;
    const int ib = blockIdx.y;
    const int rg = tid >> 3, pg = tid & 7;
    const int r0 = rg * 5, px0 = pg * 8;
    float acc[5][8] = {};

    for (int c0 = 0; c0 < CCH; c0 += 64) {
        __syncthreads();
        for (int idx = tid; idx < 1024; idx += 256) {
            int c = idx >> 4, q4 = idx & 15;
            float4 v = *(const float4*)&x[(size_t)(c0 + c) * N_PIX + n0 + q4 * 4];
            *(float4*)&xs[c][q4 * 4] = v;
        }
        for (int idx = tid; idx < 2560; idx += 256) {
            int rr = idx >> 4, c4 = idx & 15;
            const float* Wsrc;
            if (rr < 16)      Wsrc = Wq + (size_t)rr * CCH;
            else if (rr < 32) Wsrc = Wk + (size_t)(rr - 16) * CCH;
            else              Wsrc = Wv + (size_t)(rr - 32) * CCH;
            float4 wv = *(const float4*)&Wsrc[c0 + c4 * 4];
            wsm[rr][c4 * 4 + 0] = wv.x; wsm[rr][c4 * 4 + 1] = wv.y;
            wsm[rr][c4 * 4 + 2] = wv.z; wsm[rr][c4 * 4 + 3] = wv.w;
        }
        __syncthreads();
        for (int c = 0; c < 64; ++c) {
            float xv[8];
            float4 xa = *(float4*)&xs[c][px0];
            float4 xb = *(float4*)&xs[c][px0 + 4];
            xv[0] = xa.x; xv[1] = xa.y; xv[2] = xa.z; xv[3] = xa.w;
            xv[4] = xb.x; xv[5] = xb.y; xv[6] = xb.z; xv[7] = xb.w;
            #pragma unroll
            for (int j = 0; j < 5; ++j) {
                float wv = wsm[r0 + j][c];
                #pragma unroll
                for (int p2 = 0; p2 < 8; ++p2) acc[j][p2] += wv * xv[p2];
            }
        }
    }

    #pragma unroll
    for (int j = 0; j < 5; ++j) {
        int rr = r0 + j;
        if (rr < 16) {
            float bias = bq[rr];
            for (int p2 = 0; p2 < 8; ++p2)
                qb[((size_t)ib * N_PIX + n0 + px0 + p2) * 16 + rr] = f2bf(acc[j][p2] + bias);
        } else if (rr < 32) {
            float bias = bk[rr - 16];
            for (int p2 = 0; p2 < 8; ++p2)
                kb[((size_t)ib * N_PIX + n0 + px0 + p2) * 16 + (rr - 16)] = f2bf(acc[j][p2] + bias);
        } else {
            float bias = bv[rr - 32];
            short8 s8;
            for (int p2 = 0; p2 < 8; ++p2) s8[p2] = f2bf(acc[j][p2] + bias);
            *(short8*)&vb[((size_t)ib * DV + (rr - 32)) * N_PIX + n0 + px0] = s8;
        }
    }
}

// ---------------------------------------------------------------------------
// K2: MFMA flash attention (unchanged from round 2)
// ---------------------------------------------------------------------------
__global__ __launch_bounds__(256) void attn_kernel(
    const short* __restrict__ qg, const short* __restrict__ kg,
    const short* __restrict__ vg,
    const float* __restrict__ x1, const float* __restrict__ x2,
    const float* __restrict__ gamma_p,
    float* __restrict__ out1, float* __restrict__ out2)
{
    __shared__ short k_lds[2][32 * 24];
    __shared__ short v_lds[2][128 * 40];
    __shared__ short p_lds[4][16 * 40];
    __shared__ float l_lds[4][16];

    const int tid = threadIdx.x;
    const int lane = tid & 63;
    const int w = tid >> 6;
    const int B_ = blockIdx.x;
    const int res = B_ & 7;
    const int p = res >> 1;
    const int xt = ((B_ >> 3) << 1) | (res & 1);
    const int br = p >> 1, b = p & 1;
    const int n0 = xt * 64;

    const short* qp = qg + (size_t)(br * 2 + b) * N_PIX * 16;
    const short* kp = kg + (size_t)((br ^ 1) * 2 + b) * N_PIX * 16;
    const short* vp = vg + (size_t)(br * 2 + b) * DV * N_PIX;
    const float* xsg = (br ? x2 : x1) + (size_t)b * CCH * N_PIX;
    float* op = (br ? out2 : out1) + (size_t)b * CCH * N_PIX;

    const int g = lane >> 4;
    const int l15 = lane & 15;

    bf16x8 aq = {};
    if (lane < 32)
        aq = *(const bf16x8*)&qp[((size_t)(n0 + w * 16 + l15)) * 16 + g * 8];

    f32x4 acc[8];
    #pragma unroll
    for (int cc = 0; cc < 8; ++cc) acc[cc] = (f32x4){0.f, 0.f, 0.f, 0.f};
    float lsum[4] = {0.f, 0.f, 0.f, 0.f};

    const int vc = tid >> 1, vh = tid & 1;
    const int kr = (tid - 64) >> 1, kh = tid & 1;

    int4 vr0 = {}, vr1 = {}, kreg = {};
    {
        const int4* gsrc = (const int4*)(vp + (size_t)vc * N_PIX + vh * 16);
        vr0 = gsrc[0]; vr1 = gsrc[1];
        if (tid >= 64 && tid < 128)
            kreg = *(const int4*)(kp + (size_t)kr * 16 + kh * 8);
        int4* vd = (int4*)&v_lds[0][vc * 40 + vh * 16];
        vd[0] = vr0; vd[1] = vr1;
        if (tid >= 64 && tid < 128)
            *(int4*)&k_lds[0][kr * 24 + kh * 8] = kreg;
    }
    __syncthreads();

    for (int t = 0; t < 128; ++t) {
        const int cur = t & 1;
        if (t < 127) {
            const int m0n = (t + 1) * 32;
            const int4* gsrc = (const int4*)(vp + (size_t)vc * N_PIX + m0n + vh * 16);
            vr0 = gsrc[0]; vr1 = gsrc[1];
            if (tid >= 64 && tid < 128)
                kreg = *(const int4*)(kp + (size_t)(m0n + kr) * 16 + kh * 8);
        }
        #pragma unroll
        for (int h = 0; h < 2; ++h) {
            bf16x8 bk_ = {};
            if (lane < 32)
                bk_ = *(const bf16x8*)&k_lds[cur][(h * 16 + l15) * 24 + g * 8];
            f32x4 s = __builtin_amdgcn_mfma_f32_16x16x32_bf16(
                aq, bk_, (f32x4){0.f, 0.f, 0.f, 0.f}, 0, 0, 0);
            #pragma unroll
            for (int rr = 0; rr < 4; ++rr) {
                float e = __expf(s[rr] * 0.25f);
                lsum[rr] += e;
                p_lds[w][(g * 4 + rr) * 40 + h * 16 + l15] = f2bf(e);
            }
        }
        bf16x8 bp = *(const bf16x8*)&p_lds[w][l15 * 40 + g * 8];
        #pragma unroll
        for (int cc = 0; cc < 8; ++cc) {
            bf16x8 av = *(const bf16x8*)&v_lds[cur][(cc * 16 + l15) * 40 + g * 8];
            acc[cc] = __builtin_amdgcn_mfma_f32_16x16x32_bf16(av, bp, acc[cc], 0, 0, 0);
        }
        if (t < 127) {
            int4* vd = (int4*)&v_lds[cur ^ 1][vc * 40 + vh * 16];
            vd[0] = vr0; vd[1] = vr1;
            if (tid >= 64 && tid < 128)
                *(int4*)&k_lds[cur ^ 1][kr * 24 + kh * 8] = kreg;
        }
        __syncthreads();
    }

    #pragma unroll
    for (int rr = 0; rr < 4; ++rr) {
        float v = lsum[rr];
        v += __shfl_xor(v, 1); v += __shfl_xor(v, 2);
        v += __shfl_xor(v, 4); v += __shfl_xor(v, 8);
        lsum[rr] = v;
    }
    if (l15 == 0) {
        #pragma unroll
        for (int rr = 0; rr < 4; ++rr) l_lds[w][g * 4 + rr] = lsum[rr];
    }
    const float gmm = gamma_p[0];
    float linv = 1.0f / l_lds[w][l15];
    const int n = n0 + w * 16 + l15;
    #pragma unroll
    for (int cc = 0; cc < 8; ++cc) {
        #pragma unroll
        for (int rr = 0; rr < 4; ++rr) {
            int c = cc * 16 + g * 4 + rr;
            op[(size_t)c * N_PIX + n] = gmm * acc[cc][rr] * linv + xsg[(size_t)c * N_PIX + n];
        }
    }
    for (int idx = tid; idx < 128 * 16; idx += 256) {
        int c = (idx >> 4) + 128, q4 = idx & 15;
        float4 xl = *(const float4*)&xsg[(size_t)(c - 128) * N_PIX + n0 + q4 * 4];
        float4 xh = *(const float4*)&xsg[(size_t)c * N_PIX + n0 + q4 * 4];
        float4 o;
        o.x = gmm * xl.x + xh.x; o.y = gmm * xl.y + xh.y;
        o.z = gmm * xl.z + xh.z; o.w = gmm * xl.w + xh.w;
        *(float4*)&op[(size_t)c * N_PIX + n0 + q4 * 4] = o;
    }
}

// ---------------------------------------------------------------------------
// K3a: prep_s — s_t[b][px][c] bf16 = out1 + out2, transposed via LDS.
// grid (64, 2): x = row h, y = batch. block 256.
// ---------------------------------------------------------------------------
__global__ __launch_bounds__(256) void prep_s(
    const float* __restrict__ out1, const float* __restrict__ out2,
    short* __restrict__ s_t)
{
    __shared__ short st[64 * 264];   // [px][c], pitch 264
    const int tid = threadIdx.x;
    const int px0 = blockIdx.x * 64;
    const int b = blockIdx.y;
    const float* p1 = out1 + (size_t)b * CCH * N_PIX;
    const float* p2 = out2 + (size_t)b * CCH * N_PIX;

    for (int idx = tid; idx < 4096; idx += 256) {
        int c = idx >> 4, p4 = idx & 15;
        size_t off = (size_t)c * N_PIX + px0 + p4 * 4;
        float4 v1 = *(const float4*)&p1[off];
        float4 v2 = *(const float4*)&p2[off];
        st[(p4 * 4 + 0) * 264 + c] = f2bf(v1.x + v2.x);
        st[(p4 * 4 + 1) * 264 + c] = f2bf(v1.y + v2.y);
        st[(p4 * 4 + 2) * 264 + c] = f2bf(v1.z + v2.z);
        st[(p4 * 4 + 3) * 264 + c] = f2bf(v1.w + v2.w);
    }
    __syncthreads();
    for (int idx = tid; idx < 2048; idx += 256) {
        int px = idx >> 5, seg = idx & 31;
        int4 v = *(const int4*)&st[px * 264 + seg * 8];
        *(int4*)&s_t[((size_t)b * N_PIX + px0 + px) * CCH + seg * 8] = v;
    }
}

// ---------------------------------------------------------------------------
// K3b: prep_w — Wcat fp32 [oc][ic][3][3] -> wfmt bf16 A-fragment order:
//      [tap][chunk8][ocg16][lane64][8]  (oc = ocg*16 + (lane&15),
//       ic = chunk*32 + (lane>>4)*8 + j)
// grid 288, block 256: one 16B fragment slice per thread.
// ---------------------------------------------------------------------------
__global__ __launch_bounds__(256) void prep_w(
    const float* __restrict__ Wcat, short* __restrict__ wfmt)
{
    int idx = blockIdx.x * 256 + threadIdx.x;   // 0..73727
    int lane = idx & 63;
    int ocg = (idx >> 6) & 15;
    int chunk = (idx >> 10) & 7;
    int tap = idx >> 13;
    int oc = ocg * 16 + (lane & 15);
    int ic0 = chunk * 32 + (lane >> 4) * 8;
    short8 v;
    #pragma unroll
    for (int j = 0; j < 8; ++j)
        v[j] = f2bf(Wcat[((size_t)oc * CCH + ic0 + j) * 9 + tap]);
    *(short8*)&wfmt[(size_t)idx * 8] = v;
}

// ---------------------------------------------------------------------------
// K3c: conv as implicit GEMM on MFMA. 9 shifted 1x1 GEMMs, K=ic chunks of 32.
// Block: 64 oc x 128 px (2 rows of 64). 4 waves; wave -> 2 px-frags x 4 ocg
// (each B ds_read feeds 4 MFMAs). A-frags direct from L2-resident wfmt.
// grid 256: bx&3 = oc tile, bx>>2 = px tile (b, 2-row strip).
// ---------------------------------------------------------------------------
__global__ __launch_bounds__(256) void conv_mfma(
    const short* __restrict__ s_t, const short* __restrict__ wfmt,
    const float* __restrict__ bn_gamma, const float* __restrict__ bn_beta,
    float* __restrict__ feat)
{
    __shared__ short s_lds[264 * 40];   // [row 0..3][wi 0..65][ic], pitch 40
    const int tid = threadIdx.x;
    const int lane = tid & 63;
    const int wv = tid >> 6;
    const int g = lane >> 4, l15 = lane & 15;

    const int bx = blockIdx.x;
    const int oc_t = bx & 3;
    const int pt = bx >> 2;
    const int b = pt >> 5;
    const int h0 = (pt & 31) * 2;

    f32x4 acc[2][4] = {};   // [pxfrag][ocg]

    const short* sbase = s_t + (size_t)b * N_PIX * CCH;
    const short* wf = wfmt + ((size_t)(oc_t * 4) * 64 + lane) * 8;

    for (int ci = 0; ci < 8; ++ci) {
        const int ic0 = ci * 32;
        __syncthreads();
        for (int idx = tid; idx < 1056; idx += 256) {
            int seg = idx & 3, pos = idx >> 2;       // pos = row*66 + wi
            int row = pos / 66, wi = pos - row * 66;
            int hr = h0 - 1 + row, w = wi - 1;
            int4 val = {0, 0, 0, 0};
            if (hr >= 0 && hr < 64 && (unsigned)w < 64u)
                val = *(const int4*)&sbase[((size_t)(hr * 64 + w)) * CCH + ic0 + seg * 8];
            *(int4*)&s_lds[pos * 40 + seg * 8] = val;
        }
        __syncthreads();

        const short* wfc = wf + (size_t)ci * 8192;   // + chunk stride (16*64*8)
        bf16x8 a0[4], a1[4];
        #pragma unroll
        for (int j = 0; j < 4; ++j) a0[j] = *(const bf16x8*)&wfc[j * 512];

        for (int tap = 0; tap < 9; ++tap) {
            bf16x8* ac = (tap & 1) ? a1 : a0;
            bf16x8* an = (tap & 1) ? a0 : a1;
            if (tap < 8) {
                const short* wfn = wfc + (size_t)(tap + 1) * 65536;
                #pragma unroll
                for (int j = 0; j < 4; ++j) an[j] = *(const bf16x8*)&wfn[j * 512];
            }
            int ky = (tap >= 6) ? 2 : (tap >= 3 ? 1 : 0);
            int kx = tap - ky * 3;
            #pragma unroll
            for (int f = 0; f < 2; ++f) {
                int fr = wv * 2 + f;
                int rl = fr >> 2, wc0 = (fr & 3) * 16;
                bf16x8 bb = *(const bf16x8*)
                    &s_lds[((rl + ky) * 66 + wc0 + l15 + kx) * 40 + g * 8];
                #pragma unroll
                for (int j = 0; j < 4; ++j)
                    acc[f][j] = __builtin_amdgcn_mfma_f32_16x16x32_bf16(
                        ac[j], bb, acc[f][j], 0, 0, 0);
            }
        }
    }

    const float inv = rsqrtf(1.0f + 1e-5f);
    #pragma unroll
    for (int f = 0; f < 2; ++f) {
        int fr = wv * 2 + f;
        int rl = fr >> 2, wc0 = (fr & 3) * 16;
        int h = h0 + rl, wcol = wc0 + l15;
        #pragma unroll
        for (int j = 0; j < 4; ++j) {
            #pragma unroll
            for (int r = 0; r < 4; ++r) {
                int oc = oc_t * 64 + j * 16 + g * 4 + r;
                float y = acc[f][j][r] * (bn_gamma[oc] * inv) + bn_beta[oc];
                feat[((size_t)b * CCH + oc) * N_PIX + h * 64 + wcol] = fmaxf(y, 0.f);
            }
        }
    }
}

// ---------------------------------------------------------------------------
extern "C" void kernel_launch(void* const* d_in, const int* in_sizes, int n_in,
                              void* d_out, int out_size, void* d_ws, size_t ws_size,
                              hipStream_t stream) {
    const float* x1    = (const float*)d_in[0];
    const float* x2    = (const float*)d_in[1];
    const float* Wq    = (const float*)d_in[2];
    const float* bq    = (const float*)d_in[3];
    const float* Wk    = (const float*)d_in[4];
    const float* bk    = (const float*)d_in[5];
    const float* Wv    = (const float*)d_in[6];
    const float* bv    = (const float*)d_in[7];
    const float* gamma = (const float*)d_in[8];
    const float* Wcat  = (const float*)d_in[9];
    const float* bng   = (const float*)d_in[10];
    const float* bnb   = (const float*)d_in[11];

    float* out  = (float*)d_out;
    float* feat = out;
    float* out1 = out + 2097152;
    float* out2 = out + 4194304;

    short* ws   = (short*)d_ws;
    short* qb   = ws;                    // 262144 shorts
    short* kb   = ws + 262144;           // 262144
    short* vb   = ws + 524288;           // 2097152
    short* s_t  = ws + 2621440;          // 2*4096*256 = 2097152
    short* wfmt = ws + 4718592;          // 589824

    prep_w<<<288, 256, 0, stream>>>(Wcat, wfmt);
    qkv_kernel<<<dim3(64, 4), 256, 0, stream>>>(x1, x2, Wq, bq, Wk, bk, Wv, bv, qb, kb, vb);
    attn_kernel<<<256, 256, 0, stream>>>(qb, kb, vb, x1, x2, gamma, out1, out2);
    prep_s<<<dim3(64, 2), 256, 0, stream>>>(out1, out2, s_t);
    conv_mfma<<<256, 256, 0, stream>>>(s_t, wfmt, bng, bnb, feat);
}

// Round 5
// 149.177 us; speedup vs baseline: 5.3826x; 1.1429x over previous
//
#include <hip/hip_runtime.h>

#define N_PIX 4096
#define CCH 256
#define DV 128

typedef __attribute__((ext_vector_type(8))) short bf16x8;
typedef __attribute__((ext_vector_type(4))) float f32x4;
typedef __attribute__((ext_vector_type(8))) short short8;

__device__ __forceinline__ short f2bf(float f) {
    unsigned u = __builtin_bit_cast(unsigned, f);
    u += 0x7fffu + ((u >> 16) & 1u);
    return (short)(u >> 16);
}

// ---------------------------------------------------------------------------
// K1: fused 1x1 convs (register-tiled fp32 GEMM, W staged in LDS) ->
//     qb[ib][n][16] bf16, kb[ib][n][16] bf16, vb[ib][c][N] bf16
// ---------------------------------------------------------------------------
__global__ __launch_bounds__(256) void qkv_kernel(
    const float* __restrict__ x1, const float* __restrict__ x2,
    const float* __restrict__ Wq, const float* __restrict__ bq,
    const float* __restrict__ Wk, const float* __restrict__ bk,
    const float* __restrict__ Wv, const float* __restrict__ bv,
    short* __restrict__ qb, short* __restrict__ kb, short* __restrict__ vb)
{
    __shared__ float xs[64][64];
    __shared__ float wsm[160][65];
    const int tid = threadIdx.x;
    const int n0 = blockIdx.x * 64;
    const int i = blockIdx.y >> 1, b = blockIdx.y & 1;
    const float* x = (i == 0 ? x1 : x2) + (size_t)b * CCH * N_PIX;
    const int ib = blockIdx.y;
    const int rg = tid >> 3, pg = tid & 7;
    const int r0 = rg * 5, px0 = pg * 8;
    float acc[5][8] = {};

    for (int c0 = 0; c0 < CCH; c0 += 64) {
        __syncthreads();
        for (int idx = tid; idx < 1024; idx += 256) {
            int c = idx >> 4, q4 = idx & 15;
            float4 v = *(const float4*)&x[(size_t)(c0 + c) * N_PIX + n0 + q4 * 4];
            *(float4*)&xs[c][q4 * 4] = v;
        }
        for (int idx = tid; idx < 2560; idx += 256) {
            int rr = idx >> 4, c4 = idx & 15;
            const float* Wsrc;
            if (rr < 16)      Wsrc = Wq + (size_t)rr * CCH;
            else if (rr < 32) Wsrc = Wk + (size_t)(rr - 16) * CCH;
            else              Wsrc = Wv + (size_t)(rr - 32) * CCH;
            float4 wv = *(const float4*)&Wsrc[c0 + c4 * 4];
            wsm[rr][c4 * 4 + 0] = wv.x; wsm[rr][c4 * 4 + 1] = wv.y;
            wsm[rr][c4 * 4 + 2] = wv.z; wsm[rr][c4 * 4 + 3] = wv.w;
        }
        __syncthreads();
        for (int c = 0; c < 64; ++c) {
            float xv[8];
            float4 xa = *(float4*)&xs[c][px0];
            float4 xb = *(float4*)&xs[c][px0 + 4];
            xv[0] = xa.x; xv[1] = xa.y; xv[2] = xa.z; xv[3] = xa.w;
            xv[4] = xb.x; xv[5] = xb.y; xv[6] = xb.z; xv[7] = xb.w;
            #pragma unroll
            for (int j = 0; j < 5; ++j) {
                float wv = wsm[r0 + j][c];
                #pragma unroll
                for (int p2 = 0; p2 < 8; ++p2) acc[j][p2] += wv * xv[p2];
            }
        }
    }

    #pragma unroll
    for (int j = 0; j < 5; ++j) {
        int rr = r0 + j;
        if (rr < 16) {
            float bias = bq[rr];
            for (int p2 = 0; p2 < 8; ++p2)
                qb[((size_t)ib * N_PIX + n0 + px0 + p2) * 16 + rr] = f2bf(acc[j][p2] + bias);
        } else if (rr < 32) {
            float bias = bk[rr - 16];
            for (int p2 = 0; p2 < 8; ++p2)
                kb[((size_t)ib * N_PIX + n0 + px0 + p2) * 16 + (rr - 16)] = f2bf(acc[j][p2] + bias);
        } else {
            float bias = bv[rr - 32];
            short8 s8;
            for (int p2 = 0; p2 < 8; ++p2) s8[p2] = f2bf(acc[j][p2] + bias);
            *(short8*)&vb[((size_t)ib * DV + (rr - 32)) * N_PIX + n0 + px0] = s8;
        }
    }
}

// ---------------------------------------------------------------------------
// K2: MFMA flash attention with 2-way m-split (flash partials).
// grid 512: bid&7 = (pb*2+mh), bid>>3 = 64-row n-tile. 4 waves/block.
// Streams 2048 m in 32 chunks of 64; writes unnormalized partial O (f32)
// + partial row-sums l. Merge kernel divides.
// Pitches (shorts): k 24, v 72, p 72 — p pitch MUST be >= KVBLK=64
// (round-4 bug: pitch 48 < 64 made P rows overlap).
// ---------------------------------------------------------------------------
__global__ __launch_bounds__(256) void attn_kernel(
    const short* __restrict__ qg, const short* __restrict__ kg,
    const short* __restrict__ vg,
    float* __restrict__ out1, float* __restrict__ out2,
    float* __restrict__ feat, float* __restrict__ lpart)
{
    __shared__ short k_lds[2][64 * 24];    // [m][d]
    __shared__ short v_lds[2][128 * 72];   // [c][m]
    __shared__ short p_lds[4][16 * 72];    // per-wave [n][m]

    const int tid = threadIdx.x;
    const int lane = tid & 63;
    const int w = tid >> 6;
    const int B_ = blockIdx.x;
    const int pm = B_ & 7;
    const int pb = pm >> 1, mh = pm & 1;
    const int n0 = (B_ >> 3) * 64;
    const int br = pb >> 1, b = pb & 1;

    const short* qp = qg + (size_t)pb * N_PIX * 16;
    const short* kp = kg + (size_t)((br ^ 1) * 2 + b) * N_PIX * 16 + (size_t)(mh * 2048) * 16;
    const short* vp = vg + (size_t)pb * DV * N_PIX + mh * 2048;

    const int g = lane >> 4, l15 = lane & 15;

    // constant Q A-fragment (lanes>=32 zero-pad d 16..31)
    bf16x8 aq = {};
    if (lane < 32)
        aq = *(const bf16x8*)&qp[(size_t)(n0 + w * 16 + l15) * 16 + g * 8];

    f32x4 acc[8];
    #pragma unroll
    for (int cc = 0; cc < 8; ++cc) acc[cc] = (f32x4){0.f, 0.f, 0.f, 0.f};
    float lsum[4] = {0.f, 0.f, 0.f, 0.f};

    const int vc = tid >> 1, vh = tid & 1;               // V: row, 64B half
    const int t2 = tid & 127, kr = t2 >> 1, kh = t2 & 1; // K: threads 128..255

    int4 vr[4]; int4 kreg = {};
    {   // prologue: chunk 0
        const int4* gsrc = (const int4*)(vp + (size_t)vc * N_PIX + vh * 32);
        #pragma unroll
        for (int j = 0; j < 4; ++j) vr[j] = gsrc[j];
        if (tid >= 128)
            kreg = *(const int4*)&kp[(size_t)kr * 16 + kh * 8];
        int4* vd = (int4*)&v_lds[0][vc * 72 + vh * 32];
        #pragma unroll
        for (int j = 0; j < 4; ++j) vd[j] = vr[j];
        if (tid >= 128)
            *(int4*)&k_lds[0][kr * 24 + kh * 8] = kreg;
    }
    __syncthreads();

    for (int t = 0; t < 32; ++t) {
        const int cur = t & 1;
        if (t < 31) {   // issue next-chunk global loads early
            const int m0n = (t + 1) * 64;
            const int4* gsrc = (const int4*)(vp + (size_t)vc * N_PIX + m0n + vh * 32);
            #pragma unroll
            for (int j = 0; j < 4; ++j) vr[j] = gsrc[j];
            if (tid >= 128)
                kreg = *(const int4*)&kp[(size_t)(m0n + kr) * 16 + kh * 8];
        }
        // QK^T over 4 m-halves of 16 -> exp -> P (bf16, truncated) in LDS
        #pragma unroll
        for (int h = 0; h < 4; ++h) {
            bf16x8 bk_ = {};
            if (lane < 32)
                bk_ = *(const bf16x8*)&k_lds[cur][(h * 16 + l15) * 24 + g * 8];
            f32x4 s = __builtin_amdgcn_mfma_f32_16x16x32_bf16(
                aq, bk_, (f32x4){0.f, 0.f, 0.f, 0.f}, 0, 0, 0);
            #pragma unroll
            for (int rr = 0; rr < 4; ++rr) {
                float e = __expf(s[rr] * 0.25f);
                lsum[rr] += e;
                unsigned u = __builtin_bit_cast(unsigned, e);
                p_lds[w][(g * 4 + rr) * 72 + h * 16 + l15] = (short)(u >> 16);
            }
        }
        // PV: O^T[c][n] += V[c][m] * P^T[m][n], two 32-m sub-chunks
        #pragma unroll
        for (int m2 = 0; m2 < 2; ++m2) {
            bf16x8 bp = *(const bf16x8*)&p_lds[w][l15 * 72 + m2 * 32 + g * 8];
            #pragma unroll
            for (int cc = 0; cc < 8; ++cc) {
                bf16x8 av = *(const bf16x8*)&v_lds[cur][(cc * 16 + l15) * 72 + m2 * 32 + g * 8];
                acc[cc] = __builtin_amdgcn_mfma_f32_16x16x32_bf16(av, bp, acc[cc], 0, 0, 0);
            }
        }
        if (t < 31) {   // write next chunk to other buffer
            int4* vd = (int4*)&v_lds[cur ^ 1][vc * 72 + vh * 32];
            #pragma unroll
            for (int j = 0; j < 4; ++j) vd[j] = vr[j];
            if (tid >= 128)
                *(int4*)&k_lds[cur ^ 1][kr * 24 + kh * 8] = kreg;
        }
        __syncthreads();
    }

    // reduce l across the 16 m-lanes; store partial sums
    #pragma unroll
    for (int rr = 0; rr < 4; ++rr) {
        float v = lsum[rr];
        v += __shfl_xor(v, 1); v += __shfl_xor(v, 2);
        v += __shfl_xor(v, 4); v += __shfl_xor(v, 8);
        lsum[rr] = v;
    }
    if (l15 == 0) {
        #pragma unroll
        for (int rr = 0; rr < 4; ++rr)
            lpart[(size_t)pm * N_PIX + n0 + w * 16 + g * 4 + rr] = lsum[rr];
    }

    // partial O: mh=0 -> final out region (c<128 slots, merged in-place);
    //            mh=1 -> feat region scratch (conv overwrites later)
    float* Od = (mh == 0)
        ? ((br ? out2 : out1) + (size_t)b * CCH * N_PIX)
        : (feat + (size_t)pb * 128 * N_PIX);
    const int n = n0 + w * 16 + l15;
    #pragma unroll
    for (int cc = 0; cc < 8; ++cc) {
        #pragma unroll
        for (int rr = 0; rr < 4; ++rr) {
            int c = cc * 16 + g * 4 + rr;
            Od[(size_t)c * N_PIX + n] = acc[cc][rr];
        }
    }
}

// ---------------------------------------------------------------------------
// K2b: merge partials + epilogue: out = gamma*(O0+O1)/(l0+l1) + x_self,
//      channels 128..255: gamma*x_self[c-128] + x_self[c].
// ---------------------------------------------------------------------------
__global__ __launch_bounds__(256) void merge_kernel(
    const float* __restrict__ x1, const float* __restrict__ x2,
    const float* __restrict__ feat, const float* __restrict__ lpart,
    const float* __restrict__ gamma_p,
    float* __restrict__ out1, float* __restrict__ out2)
{
    __shared__ float rls[64];
    const int tid = threadIdx.x;
    const int n0 = blockIdx.x * 64;
    const int pb = blockIdx.y;
    const int br = pb >> 1, b = pb & 1;
    float* outreg = (br ? out2 : out1) + (size_t)b * CCH * N_PIX;
    const float* O1 = feat + (size_t)pb * 128 * N_PIX;
    const float* xsg = (br ? x2 : x1) + (size_t)b * CCH * N_PIX;

    if (tid < 64) {
        float l0 = lpart[(size_t)(pb * 2) * N_PIX + n0 + tid];
        float l1 = lpart[(size_t)(pb * 2 + 1) * N_PIX + n0 + tid];
        rls[tid] = 1.0f / (l0 + l1);
    }
    __syncthreads();
    const float gmm = gamma_p[0];

    for (int idx = tid; idx < 2048; idx += 256) {
        int c = idx >> 4, q = idx & 15;
        size_t off = (size_t)c * N_PIX + n0 + q * 4;
        float4 o0 = *(const float4*)&outreg[off];
        float4 o1 = *(const float4*)&O1[off];
        float4 xv = *(const float4*)&xsg[off];
        float4 r;
        r.x = gmm * (o0.x + o1.x) * rls[q * 4 + 0] + xv.x;
        r.y = gmm * (o0.y + o1.y) * rls[q * 4 + 1] + xv.y;
        r.z = gmm * (o0.z + o1.z) * rls[q * 4 + 2] + xv.z;
        r.w = gmm * (o0.w + o1.w) * rls[q * 4 + 3] + xv.w;
        *(float4*)&outreg[off] = r;
    }
    for (int idx = tid; idx < 2048; idx += 256) {
        int c = (idx >> 4) + 128, q = idx & 15;
        size_t off  = (size_t)c * N_PIX + n0 + q * 4;
        size_t offl = (size_t)(c - 128) * N_PIX + n0 + q * 4;
        float4 xl = *(const float4*)&xsg[offl];
        float4 xh = *(const float4*)&xsg[off];
        float4 r;
        r.x = gmm * xl.x + xh.x; r.y = gmm * xl.y + xh.y;
        r.z = gmm * xl.z + xh.z; r.w = gmm * xl.w + xh.w;
        *(float4*)&outreg[off] = r;
    }
}

// ---------------------------------------------------------------------------
// K3a: prep_s — s_t[b][px][c] bf16 = out1 + out2, transposed via LDS.
// ---------------------------------------------------------------------------
__global__ __launch_bounds__(256) void prep_s(
    const float* __restrict__ out1, const float* __restrict__ out2,
    short* __restrict__ s_t)
{
    __shared__ short st[64 * 264];
    const int tid = threadIdx.x;
    const int px0 = blockIdx.x * 64;
    const int b = blockIdx.y;
    const float* p1 = out1 + (size_t)b * CCH * N_PIX;
    const float* p2 = out2 + (size_t)b * CCH * N_PIX;

    for (int idx = tid; idx < 4096; idx += 256) {
        int c = idx >> 4, p4 = idx & 15;
        size_t off = (size_t)c * N_PIX + px0 + p4 * 4;
        float4 v1 = *(const float4*)&p1[off];
        float4 v2 = *(const float4*)&p2[off];
        st[(p4 * 4 + 0) * 264 + c] = f2bf(v1.x + v2.x);
        st[(p4 * 4 + 1) * 264 + c] = f2bf(v1.y + v2.y);
        st[(p4 * 4 + 2) * 264 + c] = f2bf(v1.z + v2.z);
        st[(p4 * 4 + 3) * 264 + c] = f2bf(v1.w + v2.w);
    }
    __syncthreads();
    for (int idx = tid; idx < 2048; idx += 256) {
        int px = idx >> 5, seg = idx & 31;
        int4 v = *(const int4*)&st[px * 264 + seg * 8];
        *(int4*)&s_t[((size_t)b * N_PIX + px0 + px) * CCH + seg * 8] = v;
    }
}

// ---------------------------------------------------------------------------
// K3b: prep_w — Wcat fp32 [oc][ic][3][3] -> bf16 A-fragment order
// ---------------------------------------------------------------------------
__global__ __launch_bounds__(256) void prep_w(
    const float* __restrict__ Wcat, short* __restrict__ wfmt)
{
    int idx = blockIdx.x * 256 + threadIdx.x;
    int lane = idx & 63;
    int ocg = (idx >> 6) & 15;
    int chunk = (idx >> 10) & 7;
    int tap = idx >> 13;
    int oc = ocg * 16 + (lane & 15);
    int ic0 = chunk * 32 + (lane >> 4) * 8;
    short8 v;
    #pragma unroll
    for (int j = 0; j < 8; ++j)
        v[j] = f2bf(Wcat[((size_t)oc * CCH + ic0 + j) * 9 + tap]);
    *(short8*)&wfmt[(size_t)idx * 8] = v;
}

// ---------------------------------------------------------------------------
// K3c: conv as implicit GEMM on MFMA (unchanged)
// ---------------------------------------------------------------------------
__global__ __launch_bounds__(256) void conv_mfma(
    const short* __restrict__ s_t, const short* __restrict__ wfmt,
    const float* __restrict__ bn_gamma, const float* __restrict__ bn_beta,
    float* __restrict__ feat)
{
    __shared__ short s_lds[264 * 40];
    const int tid = threadIdx.x;
    const int lane = tid & 63;
    const int wv = tid >> 6;
    const int g = lane >> 4, l15 = lane & 15;

    const int bx = blockIdx.x;
    const int oc_t = bx & 3;
    const int pt = bx >> 2;
    const int b = pt >> 5;
    const int h0 = (pt & 31) * 2;

    f32x4 acc[2][4] = {};

    const short* sbase = s_t + (size_t)b * N_PIX * CCH;
    const short* wf = wfmt + ((size_t)(oc_t * 4) * 64 + lane) * 8;

    for (int ci = 0; ci < 8; ++ci) {
        const int ic0 = ci * 32;
        __syncthreads();
        for (int idx = tid; idx < 1056; idx += 256) {
            int seg = idx & 3, pos = idx >> 2;
            int row = pos / 66, wi = pos - row * 66;
            int hr = h0 - 1 + row, w = wi - 1;
            int4 val = {0, 0, 0, 0};
            if (hr >= 0 && hr < 64 && (unsigned)w < 64u)
                val = *(const int4*)&sbase[((size_t)(hr * 64 + w)) * CCH + ic0 + seg * 8];
            *(int4*)&s_lds[pos * 40 + seg * 8] = val;
        }
        __syncthreads();

        const short* wfc = wf + (size_t)ci * 8192;
        bf16x8 a0[4], a1[4];
        #pragma unroll
        for (int j = 0; j < 4; ++j) a0[j] = *(const bf16x8*)&wfc[j * 512];

        for (int tap = 0; tap < 9; ++tap) {
            bf16x8* ac = (tap & 1) ? a1 : a0;
            bf16x8* an = (tap & 1) ? a0 : a1;
            if (tap < 8) {
                const short* wfn = wfc + (size_t)(tap + 1) * 65536;
                #pragma unroll
                for (int j = 0; j < 4; ++j) an[j] = *(const bf16x8*)&wfn[j * 512];
            }
            int ky = (tap >= 6) ? 2 : (tap >= 3 ? 1 : 0);
            int kx = tap - ky * 3;
            #pragma unroll
            for (int f = 0; f < 2; ++f) {
                int fr = wv * 2 + f;
                int rl = fr >> 2, wc0 = (fr & 3) * 16;
                bf16x8 bb = *(const bf16x8*)
                    &s_lds[((rl + ky) * 66 + wc0 + l15 + kx) * 40 + g * 8];
                #pragma unroll
                for (int j = 0; j < 4; ++j)
                    acc[f][j] = __builtin_amdgcn_mfma_f32_16x16x32_bf16(
                        ac[j], bb, acc[f][j], 0, 0, 0);
            }
        }
    }

    const float inv = rsqrtf(1.0f + 1e-5f);
    #pragma unroll
    for (int f = 0; f < 2; ++f) {
        int fr = wv * 2 + f;
        int rl = fr >> 2, wc0 = (fr & 3) * 16;
        int h = h0 + rl, wcol = wc0 + l15;
        #pragma unroll
        for (int j = 0; j < 4; ++j) {
            #pragma unroll
            for (int r = 0; r < 4; ++r) {
                int oc = oc_t * 64 + j * 16 + g * 4 + r;
                float y = acc[f][j][r] * (bn_gamma[oc] * inv) + bn_beta[oc];
                feat[((size_t)b * CCH + oc) * N_PIX + h * 64 + wcol] = fmaxf(y, 0.f);
            }
        }
    }
}

// ---------------------------------------------------------------------------
extern "C" void kernel_launch(void* const* d_in, const int* in_sizes, int n_in,
                              void* d_out, int out_size, void* d_ws, size_t ws_size,
                              hipStream_t stream) {
    const float* x1    = (const float*)d_in[0];
    const float* x2    = (const float*)d_in[1];
    const float* Wq    = (const float*)d_in[2];
    const float* bq    = (const float*)d_in[3];
    const float* Wk    = (const float*)d_in[4];
    const float* bk    = (const float*)d_in[5];
    const float* Wv    = (const float*)d_in[6];
    const float* bv    = (const float*)d_in[7];
    const float* gamma = (const float*)d_in[8];
    const float* Wcat  = (const float*)d_in[9];
    const float* bng   = (const float*)d_in[10];
    const float* bnb   = (const float*)d_in[11];

    float* out  = (float*)d_out;
    float* feat = out;
    float* out1 = out + 2097152;
    float* out2 = out + 4194304;

    short* ws   = (short*)d_ws;
    short* qb   = ws;                    // 262144 shorts
    short* kb   = ws + 262144;           // 262144
    short* vb   = ws + 524288;           // 2097152
    short* s_t  = ws + 2621440;          // 2097152 (also hosts lpart pre-merge)
    short* wfmt = ws + 4718592;          // 589824
    float* lp   = (float*)(ws + 2621440); // 8*4096 f32, dead before prep_s runs

    prep_w<<<288, 256, 0, stream>>>(Wcat, wfmt);
    qkv_kernel<<<dim3(64, 4), 256, 0, stream>>>(x1, x2, Wq, bq, Wk, bk, Wv, bv, qb, kb, vb);
    attn_kernel<<<512, 256, 0, stream>>>(qb, kb, vb, out1, out2, feat, lp);
    merge_kernel<<<dim3(64, 4), 256, 0, stream>>>(x1, x2, feat, lp, gamma, out1, out2);
    prep_s<<<dim3(64, 2), 256, 0, stream>>>(out1, out2, s_t);
    conv_mfma<<<256, 256, 0, stream>>>(s_t, wfmt, bng, bnb, feat);
}